// Round 1
// baseline (215.382 us; speedup 1.0000x reference)
//
#include <hip/hip_runtime.h>
#include <hip/hip_bf16.h>

typedef unsigned short u16;
typedef __attribute__((ext_vector_type(8))) short short8;
typedef __attribute__((ext_vector_type(4))) float float4v;

#define N_ROWS 16384   // B*H*W = 16*32*32
#define M_COLS 8192
#define KDIM   128
#define SHIFT  64.0f   // fixed logsumexp shift: A<=0, alpha=-0.5 -> exp(A+64)<=e^64, no overflow

// RNE fp32 -> bf16 (data has no NaN)
__device__ inline u16 f2bf(float f) {
  unsigned u = __builtin_bit_cast(unsigned, f);
  unsigned r = (u + 0x7fffu + ((u >> 16) & 1u)) >> 16;
  return (u16)r;
}

// ---------------------------------------------------------------------------
// prep_z: z[16,128,32,32] -> zf[n][c] bf16 (n = b*1024 + h*32 + w), zsq[n] fp32
// one block per (b,h); LDS tile [c][w] padded stride 33 (conflict-free)
// ---------------------------------------------------------------------------
__global__ void prep_z(const float* __restrict__ z, u16* __restrict__ zf,
                       float* __restrict__ zsq) {
  const int b = blockIdx.x >> 5, h = blockIdx.x & 31;
  __shared__ float tile[128 * 33];
  const float* src = z + ((size_t)b * 128 * 32 + h) * 32;  // src[c*1024 + w]
  for (int idx = threadIdx.x; idx < 4096; idx += 256) {
    int c = idx >> 5, w = idx & 31;
    tile[c * 33 + w] = src[c * 1024 + w];
  }
  __syncthreads();
  if (threadIdx.x < 32) {
    int w = threadIdx.x;
    float s = 0.f;
    for (int c = 0; c < 128; ++c) { float v = tile[c * 33 + w]; s = fmaf(v, v, s); }
    zsq[(size_t)b * 1024 + h * 32 + w] = s;
  }
  for (int idx = threadIdx.x; idx < 4096; idx += 256) {
    int w = idx >> 7, c = idx & 127;
    zf[((size_t)b * 1024 + h * 32 + w) * 128 + c] = f2bf(tile[c * 33 + w]);
  }
}

// ---------------------------------------------------------------------------
// prep_e: e[8192,128] fp32 -> ef bf16, esq[m] fp32 (wave per row for esq)
// ---------------------------------------------------------------------------
__global__ void prep_e(const float* __restrict__ e, u16* __restrict__ ef,
                       float* __restrict__ esq) {
  const int tid = blockIdx.x * 256 + threadIdx.x;  // 16384 threads
  for (int i = tid; i < M_COLS * KDIM; i += 16384) ef[i] = f2bf(e[i]);
  const int wid = tid >> 6, ln = tid & 63;
  for (int r = wid; r < M_COLS; r += 256) {
    float v0 = e[r * 128 + ln], v1 = e[r * 128 + 64 + ln];
    float s = fmaf(v0, v0, v1 * v1);
    for (int sh = 1; sh < 64; sh <<= 1) s += __shfl_xor(s, sh);
    if (ln == 0) esq[r] = s;
  }
}

// ---------------------------------------------------------------------------
// gemm_lse: 128x128 tile per block, full K=128 in LDS.
// XOR-swizzled staging: LDS write is linear (global_load_lds requirement);
// the 16B group fetched for unit u = r*16+p is g = p ^ (r&15), so fragment
// reads (which want (r, g) with r%16 == lane%16) hit <=2-way banks (free).
// Epilogue: exp(alpha*dist + S) accumulated per-row/per-col, atomicAdd out.
// ---------------------------------------------------------------------------
__global__ __launch_bounds__(256, 2) void gemm_lse(
    const u16* __restrict__ zf, const u16* __restrict__ ef,
    const float* __restrict__ zsq, const float* __restrict__ esq,
    const float* __restrict__ log_sigma,
    float* __restrict__ rowsum, float* __restrict__ colsum) {
  __shared__ __align__(16) u16 zt[128 * 128];  // 32 KB, [row][k], swizzled
  __shared__ __align__(16) u16 et[128 * 128];  // 32 KB, [col][k], swizzled
  const int tid = threadIdx.x;
  const int ln = tid & 63, wv = tid >> 6;
  const int bx = blockIdx.x, by = blockIdx.y;
  const int wr = wv >> 1, wc = wv & 1;
  const int l15 = ln & 15, q = ln >> 4;

  const u16* zsrc = zf + (size_t)by * (128 * 128);
  const u16* esrc = ef + (size_t)bx * (128 * 128);
#pragma unroll
  for (int it = 0; it < 8; ++it) {
    int u = it * 256 + wv * 64 + ln;       // linear LDS 16B-unit this lane fills
    int r = u >> 4, p = u & 15;
    int g = p ^ (r & 15);                  // swizzled source group
    int soff = r * 128 + g * 8;            // u16 offset in global
    int lbase = (it * 256 + wv * 64) * 8;  // wave-uniform LDS base (u16 units)
    __builtin_amdgcn_global_load_lds(
        (const __attribute__((address_space(1))) unsigned int*)(zsrc + soff),
        (__attribute__((address_space(3))) unsigned int*)(zt + lbase), 16, 0, 0);
    __builtin_amdgcn_global_load_lds(
        (const __attribute__((address_space(1))) unsigned int*)(esrc + soff),
        (__attribute__((address_space(3))) unsigned int*)(et + lbase), 16, 0, 0);
  }

  // per-lane row/col squared norms (L2-hot small arrays)
  float4v zsql[4];
  float esql[4];
#pragma unroll
  for (int i = 0; i < 4; ++i)
    zsql[i] = *(const float4v*)(zsq + by * 128 + wr * 64 + i * 16 + q * 4);
#pragma unroll
  for (int j = 0; j < 4; ++j)
    esql[j] = esq[bx * 128 + wc * 64 + j * 16 + l15];

  const float lsv = log_sigma[0];
  const float sg = __expf(lsv);
  const float alpha = -0.5f / (sg * sg);
  const float L2E = 1.44269504088896f;
  const float ca = alpha * L2E, cb = SHIFT * L2E;

  float4v acc[4][4];
#pragma unroll
  for (int i = 0; i < 4; ++i)
#pragma unroll
    for (int j = 0; j < 4; ++j) acc[i][j] = (float4v){0.f, 0.f, 0.f, 0.f};

  __syncthreads();

#pragma unroll
  for (int kk = 0; kk < 4; ++kk) {
    short8 af[4], bfr[4];
    const int poff = ((kk * 4 + q) ^ l15) * 8;  // u16 offset within row
#pragma unroll
    for (int i = 0; i < 4; ++i)
      af[i] = *(const short8*)(zt + (wr * 64 + i * 16 + l15) * 128 + poff);
#pragma unroll
    for (int j = 0; j < 4; ++j)
      bfr[j] = *(const short8*)(et + (wc * 64 + j * 16 + l15) * 128 + poff);
#pragma unroll
    for (int i = 0; i < 4; ++i)
#pragma unroll
      for (int j = 0; j < 4; ++j)
        acc[i][j] = __builtin_amdgcn_mfma_f32_16x16x32_bf16(af[i], bfr[j], acc[i][j], 0, 0, 0);
  }

  // epilogue: dist = zsq + esq - 2*dot, ex = exp2((alpha*dist + S)*log2e)
  float rs[4][4] = {};  // per (row-subtile i, reg) over this lane's cols
  float cs[4] = {};     // per col-subtile j over this lane's rows
#pragma unroll
  for (int i = 0; i < 4; ++i) {
#pragma unroll
    for (int j = 0; j < 4; ++j) {
      const float se = esql[j];
#pragma unroll
      for (int r = 0; r < 4; ++r) {
        float dist = fmaf(acc[i][j][r], -2.0f, zsql[i][r] + se);
        dist = fmaxf(dist, 0.f);
        float ex = exp2f(fmaf(dist, ca, cb));
        rs[i][r] += ex;
        cs[j] += ex;
      }
    }
  }
  // reduce rows across the 16 lanes of each quad (bits 0-3)
#pragma unroll
  for (int i = 0; i < 4; ++i)
#pragma unroll
    for (int r = 0; r < 4; ++r)
      for (int s = 1; s < 16; s <<= 1) rs[i][r] += __shfl_xor(rs[i][r], s);
  // reduce cols across quads (bits 4-5)
#pragma unroll
  for (int j = 0; j < 4; ++j) {
    cs[j] += __shfl_xor(cs[j], 16);
    cs[j] += __shfl_xor(cs[j], 32);
  }

  __syncthreads();  // all zt/et reads done; reuse zt as reduction buffer
  float* rbuf = (float*)zt;      // [2][128] by col-half
  float* cbuf = rbuf + 256;      // [2][128] by row-half
  if (l15 == 0) {
#pragma unroll
    for (int i = 0; i < 4; ++i)
#pragma unroll
      for (int r = 0; r < 4; ++r)
        rbuf[wc * 128 + wr * 64 + i * 16 + q * 4 + r] = rs[i][r];
  }
  if (q == 0) {
#pragma unroll
    for (int j = 0; j < 4; ++j)
      cbuf[wr * 128 + wc * 64 + j * 16 + l15] = cs[j];
  }
  __syncthreads();
  if (tid < 128) {
    atomicAdd(&rowsum[by * 128 + tid], rbuf[tid] + rbuf[128 + tid]);
  } else {
    int t = tid - 128;
    atomicAdd(&colsum[bx * 128 + t], cbuf[t] + cbuf[128 + t]);
  }
}

// ---------------------------------------------------------------------------
// finalize: block 0 -> lse1 (rows, +log M), block 1 -> lse2 (cols, +log N)
// ---------------------------------------------------------------------------
__global__ void finalize(const float* __restrict__ rowsum, const float* __restrict__ colsum,
                         const float* __restrict__ log_sigma, float* __restrict__ out) {
  const int tid = threadIdx.x;
  const bool rows = (blockIdx.x == 0);
  const int n = rows ? N_ROWS : M_COLS;
  const float* buf = rows ? rowsum : colsum;
  double part = 0.0;
  for (int i = tid; i < n; i += 256) part += (double)logf(buf[i]);
  __shared__ double red[256];
  red[tid] = part;
  __syncthreads();
  for (int s = 128; s > 0; s >>= 1) {
    if (tid < s) red[tid] += red[tid + s];
    __syncthreads();
  }
  if (tid == 0) {
    float lsv = log_sigma[0];
    float cst = 0.5f * 128.0f * (2.0f * lsv - 1.0f);
    float lother = rows ? logf((float)M_COLS) : logf((float)N_ROWS);
    // loss = -(mean(log(sum)) - S) + cst + log(other_dim)
    out[blockIdx.x] = (float)(-(red[0] / n - (double)SHIFT)) + cst + lother;
  }
}

extern "C" void kernel_launch(void* const* d_in, const int* in_sizes, int n_in,
                              void* d_out, int out_size, void* d_ws, size_t ws_size,
                              hipStream_t stream) {
  const float* z  = (const float*)d_in[0];
  const float* e  = (const float*)d_in[1];
  const float* ls = (const float*)d_in[2];
  float* out = (float*)d_out;
  char* ws = (char*)d_ws;
  u16*  zf     = (u16*)ws;                                     // 4 MB
  u16*  ef     = (u16*)(ws + (4u << 20));                      // 2 MB
  float* zsq   = (float*)(ws + (6u << 20));                    // 64 KB
  float* esq   = (float*)(ws + (6u << 20) + 65536);            // 32 KB
  float* rowsum = (float*)(ws + (6u << 20) + 65536 + 32768);   // 64 KB
  float* colsum = (float*)(ws + (6u << 20) + 65536 + 32768 + 65536);  // 32 KB

  hipMemsetAsync(rowsum, 0, 65536 + 32768, stream);  // rowsum+colsum contiguous
  prep_z<<<dim3(512), dim3(256), 0, stream>>>(z, zf, zsq);
  prep_e<<<dim3(64), dim3(256), 0, stream>>>(e, ef, esq);
  gemm_lse<<<dim3(64, 128), dim3(256), 0, stream>>>(zf, ef, zsq, esq, ls, rowsum, colsum);
  finalize<<<dim3(2), dim3(256), 0, stream>>>(rowsum, colsum, ls, out);
}

// Round 2
// 169.365 us; speedup vs baseline: 1.2717x; 1.2717x over previous
//
#include <hip/hip_runtime.h>
#include <hip/hip_bf16.h>

typedef unsigned short u16;
typedef __attribute__((ext_vector_type(8))) short short8;
typedef __attribute__((ext_vector_type(4))) float float4v;

#define N_ROWS 16384   // B*H*W = 16*32*32
#define M_COLS 8192
#define KDIM   128
#define SHIFT  64.0f   // fixed logsumexp shift: A<=0, alpha~-0.5 -> exp(A+64) in range

// RNE fp32 -> bf16 (data has no NaN)
__device__ inline u16 f2bf(float f) {
  unsigned u = __builtin_bit_cast(unsigned, f);
  unsigned r = (u + 0x7fffu + ((u >> 16) & 1u)) >> 16;
  return (u16)r;
}

// ---------------------------------------------------------------------------
// prep_z: z[16,128,32,32] -> zf[n][c] bf16 (n = b*1024+h*32+w), zsq[n] fp32
// one block per (b,h); fp32 LDS tile [c][w] pad 33; 16B vector stores out.
// ---------------------------------------------------------------------------
__global__ void prep_z(const float* __restrict__ z, u16* __restrict__ zf,
                       float* __restrict__ zsq) {
  const int b = blockIdx.x >> 5, h = blockIdx.x & 31;
  __shared__ float tile[128 * 33];
  __shared__ float psum[8][32];
  const float* src = z + ((size_t)b * 128 * 32 + h) * 32;  // + c*1024 + w
  for (int idx = threadIdx.x; idx < 4096; idx += 256) {
    int c = idx >> 5, w = idx & 31;
    tile[c * 33 + w] = src[c * 1024 + w];
  }
  __syncthreads();
  {
    int w = threadIdx.x & 31, cg = threadIdx.x >> 5;
    float s = 0.f;
#pragma unroll
    for (int cc = 0; cc < 16; ++cc) {
      float v = tile[(cg * 16 + cc) * 33 + w];
      s = fmaf(v, v, s);
    }
    psum[cg][w] = s;
  }
  // vector stores: 512 units of (w, g8): each thread does 2
  for (int idx = threadIdx.x; idx < 512; idx += 256) {
    int w = idx >> 4, g = idx & 15;
    short8 v;
#pragma unroll
    for (int cc = 0; cc < 8; ++cc) v[cc] = (short)f2bf(tile[(g * 8 + cc) * 33 + w]);
    *(short8*)&zf[((size_t)b * 1024 + h * 32 + w) * 128 + g * 8] = v;
  }
  __syncthreads();
  if (threadIdx.x < 32) {
    int w = threadIdx.x;
    float s = 0.f;
#pragma unroll
    for (int cg = 0; cg < 8; ++cg) s += psum[cg][w];
    zsq[b * 1024 + h * 32 + w] = s;
  }
}

// ---------------------------------------------------------------------------
// prep_e: e[8192,128] fp32 -> ef bf16 (packed 2x stores), esq[m] fp32.
// wave per row, float2 per lane, coalesced.
// ---------------------------------------------------------------------------
__global__ void prep_e(const float* __restrict__ e, u16* __restrict__ ef,
                       float* __restrict__ esq) {
  const int gw = (blockIdx.x * 256 + threadIdx.x) >> 6;  // 256 waves total
  const int ln = threadIdx.x & 63;
  for (int r = gw; r < M_COLS; r += 256) {
    float2 v = *(const float2*)&e[r * 128 + ln * 2];
    unsigned pk = (unsigned)f2bf(v.x) | ((unsigned)f2bf(v.y) << 16);
    *(unsigned*)&ef[r * 128 + ln * 2] = pk;
    float s = fmaf(v.x, v.x, v.y * v.y);
#pragma unroll
    for (int sh = 1; sh < 64; sh <<= 1) s += __shfl_xor(s, sh);
    if (ln == 0) esq[r] = s;
  }
}

// ---------------------------------------------------------------------------
// gemm_lse: 256x256 tile per 1024-thread block (16 waves, 4x4 of 64x64 wave
// tiles), full K=128 in LDS (128 KB). XOR-swizzled linear staging via
// global_load_lds width=16. Slim epilogue: base add + fma + v_exp_f32 +
// 2 accum adds per element; per-row/col partials -> LDS combine -> atomics.
// ---------------------------------------------------------------------------
__global__ __launch_bounds__(1024, 4) void gemm_lse(
    const u16* __restrict__ zf, const u16* __restrict__ ef,
    const float* __restrict__ zsq, const float* __restrict__ esq,
    const float* __restrict__ log_sigma,
    float* __restrict__ rowsum, float* __restrict__ colsum) {
  __shared__ __align__(16) u16 zt[256 * 128];  // 64 KB
  __shared__ __align__(16) u16 et[256 * 128];  // 64 KB
  const int tid = threadIdx.x;
  const int ln = tid & 63, wv = tid >> 6;      // wv 0..15
  const int wr = wv >> 2, wc = wv & 3;         // 4x4 wave grid
  const int l15 = ln & 15, q = ln >> 4;
  const int bx = blockIdx.x, by = blockIdx.y;

  const u16* zsrc = zf + (size_t)by * (256 * 128);
  const u16* esrc = ef + (size_t)bx * (256 * 128);
#pragma unroll
  for (int it = 0; it < 4; ++it) {
    int u = it * 1024 + tid;               // linear 16B unit
    int r = u >> 4, p = u & 15;
    int g = p ^ (r & 15);                  // swizzled source group
    int soff = r * 128 + g * 8;
    int lbase = (it * 1024 + wv * 64) * 8; // wave-uniform LDS base (u16 units)
    __builtin_amdgcn_global_load_lds(
        (const __attribute__((address_space(1))) unsigned int*)(zsrc + soff),
        (__attribute__((address_space(3))) unsigned int*)(zt + lbase), 16, 0, 0);
    __builtin_amdgcn_global_load_lds(
        (const __attribute__((address_space(1))) unsigned int*)(esrc + soff),
        (__attribute__((address_space(3))) unsigned int*)(et + lbase), 16, 0, 0);
  }

  float4v acc[4][4];
#pragma unroll
  for (int i = 0; i < 4; ++i)
#pragma unroll
    for (int j = 0; j < 4; ++j) acc[i][j] = (float4v){0.f, 0.f, 0.f, 0.f};

  __syncthreads();

#pragma unroll
  for (int kk = 0; kk < 4; ++kk) {
    short8 af[4], bfr[4];
    const int poff = ((kk * 4 + q) ^ l15) * 8;
#pragma unroll
    for (int i = 0; i < 4; ++i)
      af[i] = *(const short8*)(zt + (wr * 64 + i * 16 + l15) * 128 + poff);
#pragma unroll
    for (int j = 0; j < 4; ++j)
      bfr[j] = *(const short8*)(et + (wc * 64 + j * 16 + l15) * 128 + poff);
#pragma unroll
    for (int i = 0; i < 4; ++i)
#pragma unroll
      for (int j = 0; j < 4; ++j)
        acc[i][j] = __builtin_amdgcn_mfma_f32_16x16x32_bf16(af[i], bfr[j], acc[i][j], 0, 0, 0);
  }

  // constants: arg = (alpha*(zsq+esq-2dot) + SHIFT) * log2e = zb + eb + m2ca*dot
  const float lsv = log_sigma[0];
  const float sg = __expf(lsv);
  const float alpha = -0.5f / (sg * sg);
  const float L2E = 1.44269504088896f;
  const float ca = alpha * L2E, cb = SHIFT * L2E, m2ca = -2.0f * ca;

  float4v zb[4];
  float eb[4];
#pragma unroll
  for (int i = 0; i < 4; ++i) {
    float4v zs = *(const float4v*)(zsq + by * 256 + wr * 64 + i * 16 + q * 4);
#pragma unroll
    for (int r = 0; r < 4; ++r) zb[i][r] = fmaf(ca, zs[r], cb);
  }
#pragma unroll
  for (int j = 0; j < 4; ++j) eb[j] = ca * esq[bx * 256 + wc * 64 + j * 16 + l15];

  float rs[4][4] = {};
  float cs[4] = {};
#pragma unroll
  for (int i = 0; i < 4; ++i) {
#pragma unroll
    for (int j = 0; j < 4; ++j) {
      float ex0, ex1, ex2, ex3;
      {
        float arg = fmaf(acc[i][j][0], m2ca, zb[i][0] + eb[j]);
        ex0 = __builtin_amdgcn_exp2f(arg);
      }
      {
        float arg = fmaf(acc[i][j][1], m2ca, zb[i][1] + eb[j]);
        ex1 = __builtin_amdgcn_exp2f(arg);
      }
      {
        float arg = fmaf(acc[i][j][2], m2ca, zb[i][2] + eb[j]);
        ex2 = __builtin_amdgcn_exp2f(arg);
      }
      {
        float arg = fmaf(acc[i][j][3], m2ca, zb[i][3] + eb[j]);
        ex3 = __builtin_amdgcn_exp2f(arg);
      }
      rs[i][0] += ex0; rs[i][1] += ex1; rs[i][2] += ex2; rs[i][3] += ex3;
      cs[j] += (ex0 + ex1) + (ex2 + ex3);
    }
  }
  // reduce rows across the 16 lanes of each quad (bits 0-3)
#pragma unroll
  for (int i = 0; i < 4; ++i)
#pragma unroll
    for (int r = 0; r < 4; ++r)
      for (int s = 1; s < 16; s <<= 1) rs[i][r] += __shfl_xor(rs[i][r], s);
  // reduce cols across quads (bits 4-5)
#pragma unroll
  for (int j = 0; j < 4; ++j) {
    cs[j] += __shfl_xor(cs[j], 16);
    cs[j] += __shfl_xor(cs[j], 32);
  }

  __syncthreads();  // zt/et reads done; reuse zt as reduction buffer
  float* rbuf = (float*)zt;       // [4][256] by wc
  float* cbuf = rbuf + 1024;      // [4][256] by wr
  if (l15 == 0) {
#pragma unroll
    for (int i = 0; i < 4; ++i)
#pragma unroll
      for (int r = 0; r < 4; ++r)
        rbuf[wc * 256 + wr * 64 + i * 16 + q * 4 + r] = rs[i][r];
  }
  if (q == 0) {
#pragma unroll
    for (int j = 0; j < 4; ++j)
      cbuf[wr * 256 + wc * 64 + j * 16 + l15] = cs[j];
  }
  __syncthreads();
  if (tid < 256) {
    atomicAdd(&rowsum[by * 256 + tid],
              (rbuf[tid] + rbuf[256 + tid]) + (rbuf[512 + tid] + rbuf[768 + tid]));
  } else if (tid < 512) {
    int t = tid - 256;
    atomicAdd(&colsum[bx * 256 + t],
              (cbuf[t] + cbuf[256 + t]) + (cbuf[512 + t] + cbuf[768 + t]));
  }
}

// ---------------------------------------------------------------------------
// finalize: block 0 -> lse1 (rows, +log M), block 1 -> lse2 (cols, +log N)
// ---------------------------------------------------------------------------
__global__ void finalize(const float* __restrict__ rowsum, const float* __restrict__ colsum,
                         const float* __restrict__ log_sigma, float* __restrict__ out) {
  const int tid = threadIdx.x;
  const bool rows = (blockIdx.x == 0);
  const int n = rows ? N_ROWS : M_COLS;
  const float* buf = rows ? rowsum : colsum;
  double part = 0.0;
  for (int i = tid; i < n; i += 1024) part += (double)logf(buf[i]);
  __shared__ double red[1024];
  red[tid] = part;
  __syncthreads();
  for (int s = 512; s > 0; s >>= 1) {
    if (tid < s) red[tid] += red[tid + s];
    __syncthreads();
  }
  if (tid == 0) {
    float lsv = log_sigma[0];
    float cst = 0.5f * 128.0f * (2.0f * lsv - 1.0f);
    float lother = rows ? logf((float)M_COLS) : logf((float)N_ROWS);
    out[blockIdx.x] = (float)(-(red[0] / n - (double)SHIFT)) + cst + lother;
  }
}

extern "C" void kernel_launch(void* const* d_in, const int* in_sizes, int n_in,
                              void* d_out, int out_size, void* d_ws, size_t ws_size,
                              hipStream_t stream) {
  const float* z  = (const float*)d_in[0];
  const float* e  = (const float*)d_in[1];
  const float* ls = (const float*)d_in[2];
  float* out = (float*)d_out;
  char* ws = (char*)d_ws;
  u16*  zf     = (u16*)ws;                                     // 4 MB
  u16*  ef     = (u16*)(ws + (4u << 20));                      // 2 MB
  float* zsq   = (float*)(ws + (6u << 20));                    // 64 KB
  float* esq   = (float*)(ws + (6u << 20) + 65536);            // 32 KB
  float* rowsum = (float*)(ws + (6u << 20) + 65536 + 32768);   // 64 KB
  float* colsum = (float*)(ws + (6u << 20) + 65536 + 32768 + 65536);  // 32 KB

  hipMemsetAsync(rowsum, 0, 65536 + 32768, stream);  // rowsum+colsum contiguous
  prep_z<<<dim3(512), dim3(256), 0, stream>>>(z, zf, zsq);
  prep_e<<<dim3(64), dim3(256), 0, stream>>>(e, ef, esq);
  gemm_lse<<<dim3(32, 64), dim3(1024), 0, stream>>>(zf, ef, zsq, esq, ls, rowsum, colsum);
  finalize<<<dim3(2), dim3(1024), 0, stream>>>(rowsum, colsum, ls, out);
}

// Round 3
// 151.747 us; speedup vs baseline: 1.4194x; 1.1161x over previous
//
#include <hip/hip_runtime.h>
#include <hip/hip_bf16.h>

typedef unsigned short u16;
typedef __attribute__((ext_vector_type(8))) short short8;
typedef __attribute__((ext_vector_type(4))) float float4v;

#define N_ROWS 16384   // B*H*W = 16*32*32
#define M_COLS 8192
#define KDIM   128
#define SHIFT  64.0f   // fixed lse shift: A<=0, alpha~-0.5 -> exp(A+64) in range
#define STRIPES 64     // 16384 / 256 rows per block
#define SPLITS  8      // col splits; each block covers 1024 cols
#define TILES   16     // 1024 / 64 cols per tile

// RNE fp32 -> bf16 (data has no NaN)
__device__ inline u16 f2bf(float f) {
  unsigned u = __builtin_bit_cast(unsigned, f);
  unsigned r = (u + 0x7fffu + ((u >> 16) & 1u)) >> 16;
  return (u16)r;
}

// ---------------------------------------------------------------------------
// prep (fused): blocks 0..511 = prep_z (one per (b,h)); blocks 512..575 = prep_e
// ---------------------------------------------------------------------------
__global__ void prep(const float* __restrict__ z, const float* __restrict__ e,
                     u16* __restrict__ zf, u16* __restrict__ ef,
                     float* __restrict__ zsq, float* __restrict__ esq) {
  if (blockIdx.x < 512) {
    const int b = blockIdx.x >> 5, h = blockIdx.x & 31;
    __shared__ float tile[128 * 33];
    __shared__ float psum[8][32];
    const float* src = z + ((size_t)b * 128 * 32 + h) * 32;  // + c*1024 + w
    for (int idx = threadIdx.x; idx < 4096; idx += 256) {
      int c = idx >> 5, w = idx & 31;
      tile[c * 33 + w] = src[c * 1024 + w];
    }
    __syncthreads();
    {
      int w = threadIdx.x & 31, cg = threadIdx.x >> 5;
      float s = 0.f;
#pragma unroll
      for (int cc = 0; cc < 16; ++cc) {
        float v = tile[(cg * 16 + cc) * 33 + w];
        s = fmaf(v, v, s);
      }
      psum[cg][w] = s;
    }
    for (int idx = threadIdx.x; idx < 512; idx += 256) {
      int w = idx >> 4, g = idx & 15;
      short8 v;
#pragma unroll
      for (int cc = 0; cc < 8; ++cc) v[cc] = (short)f2bf(tile[(g * 8 + cc) * 33 + w]);
      *(short8*)&zf[((size_t)b * 1024 + h * 32 + w) * 128 + g * 8] = v;
    }
    __syncthreads();
    if (threadIdx.x < 32) {
      int w = threadIdx.x;
      float s = 0.f;
#pragma unroll
      for (int cg = 0; cg < 8; ++cg) s += psum[cg][w];
      zsq[b * 1024 + h * 32 + w] = s;
    }
  } else {
    const int gw = ((blockIdx.x - 512) * 256 + threadIdx.x) >> 6;  // 256 waves
    const int ln = threadIdx.x & 63;
    for (int r = gw; r < M_COLS; r += 256) {
      float2 v = *(const float2*)&e[r * 128 + ln * 2];
      unsigned pk = (unsigned)f2bf(v.x) | ((unsigned)f2bf(v.y) << 16);
      *(unsigned*)&ef[r * 128 + ln * 2] = pk;
      float s = fmaf(v.x, v.x, v.y * v.y);
#pragma unroll
      for (int sh = 1; sh < 64; sh <<= 1) s += __shfl_xor(s, sh);
      if (ln == 0) esq[r] = s;
    }
  }
}

// ---------------------------------------------------------------------------
// gemm_lse: persistent-A. Block = 4 waves = 256-row stripe; wave = 64 rows,
// all K=128 A-frags in regs. Loop over 16 B-tiles (64 cols) of this block's
// 1024-col split, double-buffered LDS staging via global_load_lds (XOR
// swizzle). Per iter: [barrier; mma(t); stage(t+1); epilogue(t)] so staging
// overlaps the VALU-heavy epilogue. rowsum in regs (flushed once); colsum
// via LDS ds-atomics -> non-atomic per-block global partials.
// ---------------------------------------------------------------------------
__global__ __launch_bounds__(256, 2) void gemm_lse(
    const u16* __restrict__ zf, const u16* __restrict__ ef,
    const float* __restrict__ zsq, const float* __restrict__ esq,
    const float* __restrict__ log_sigma,
    float* __restrict__ rpart, float* __restrict__ cpart) {
  __shared__ __align__(16) u16 et[2][64 * 128];  // 2 x 16 KB
  __shared__ float colacc[1024];
  const int tid = threadIdx.x;
  const int ln = tid & 63, wv = tid >> 6;
  const int l15 = ln & 15, q = ln >> 4;
  const int stripe = blockIdx.x, split = blockIdx.y;
  const int colbase = split * 1024;

  for (int i = tid; i < 1024; i += 256) colacc[i] = 0.f;

  // persistent A fragments: 64 rows x K=128 per wave (16 x short8 = 64 VGPRs)
  short8 af[4][4];
#pragma unroll
  for (int i = 0; i < 4; ++i)
#pragma unroll
    for (int kk = 0; kk < 4; ++kk)
      af[i][kk] = *(const short8*)(zf +
          (size_t)(stripe * 256 + wv * 64 + i * 16 + l15) * 128 + kk * 32 + q * 8);

  const float lsv = log_sigma[0];
  const float sg = __expf(lsv);
  const float alpha = -0.5f / (sg * sg);
  const float L2E = 1.44269504088896f;
  const float ca = alpha * L2E, cb = SHIFT * L2E, m2ca = -2.0f * ca;

  float4v zbl[4];
#pragma unroll
  for (int i = 0; i < 4; ++i) {
    float4v zs = *(const float4v*)(zsq + stripe * 256 + wv * 64 + i * 16 + q * 4);
#pragma unroll
    for (int r = 0; r < 4; ++r) zbl[i][r] = fmaf(ca, zs[r], cb);
  }

  float2 rs2[4][2];
#pragma unroll
  for (int i = 0; i < 4; ++i)
#pragma unroll
    for (int p = 0; p < 2; ++p) rs2[i][p] = make_float2(0.f, 0.f);

  // staging helper pattern (4 units of 16B per thread per tile)
#define STAGE(tt)                                                              \
  do {                                                                         \
    const u16* efb = ef + (size_t)(colbase + (tt) * 64) * 128;                 \
    u16* dstb = et[(tt) & 1];                                                  \
    _Pragma("unroll")                                                          \
    for (int it = 0; it < 4; ++it) {                                           \
      int u = it * 256 + tid;                                                  \
      int r = u >> 4, p_ = u & 15;                                             \
      int g = p_ ^ (r & 15);                                                   \
      __builtin_amdgcn_global_load_lds(                                        \
          (const __attribute__((address_space(1))) unsigned int*)(efb + r * 128 + g * 8), \
          (__attribute__((address_space(3))) unsigned int*)(dstb + (it * 256 + wv * 64) * 8), \
          16, 0, 0);                                                           \
    }                                                                          \
  } while (0)

  STAGE(0);

  for (int t = 0; t < TILES; ++t) {
    __syncthreads();
    const u16* bb = et[t & 1];

    float4v acc[4][4];
#pragma unroll
    for (int kk = 0; kk < 4; ++kk) {
      short8 bfr[4];
      const int poff = ((kk * 4 + q) ^ l15) * 8;
#pragma unroll
      for (int j = 0; j < 4; ++j)
        bfr[j] = *(const short8*)(bb + (j * 16 + l15) * 128 + poff);
      if (kk == 0) {
#pragma unroll
        for (int i = 0; i < 4; ++i)
#pragma unroll
          for (int j = 0; j < 4; ++j)
            acc[i][j] = __builtin_amdgcn_mfma_f32_16x16x32_bf16(
                af[i][0], bfr[j], (float4v){0.f, 0.f, 0.f, 0.f}, 0, 0, 0);
      } else {
#pragma unroll
        for (int i = 0; i < 4; ++i)
#pragma unroll
          for (int j = 0; j < 4; ++j)
            acc[i][j] = __builtin_amdgcn_mfma_f32_16x16x32_bf16(
                af[i][kk], bfr[j], acc[i][j], 0, 0, 0);
      }
    }

    if (t + 1 < TILES) STAGE(t + 1);  // overlaps with epilogue below

    float ebv[4];
#pragma unroll
    for (int j = 0; j < 4; ++j) ebv[j] = ca * esq[colbase + t * 64 + j * 16 + l15];

    float2 cs2[4];
#pragma unroll
    for (int j = 0; j < 4; ++j) cs2[j] = make_float2(0.f, 0.f);

#pragma unroll
    for (int i = 0; i < 4; ++i) {
#pragma unroll
      for (int j = 0; j < 4; ++j) {
        float e0 = __builtin_amdgcn_exp2f(fmaf(acc[i][j][0], m2ca, zbl[i][0] + ebv[j]));
        float e1 = __builtin_amdgcn_exp2f(fmaf(acc[i][j][1], m2ca, zbl[i][1] + ebv[j]));
        float e2 = __builtin_amdgcn_exp2f(fmaf(acc[i][j][2], m2ca, zbl[i][2] + ebv[j]));
        float e3 = __builtin_amdgcn_exp2f(fmaf(acc[i][j][3], m2ca, zbl[i][3] + ebv[j]));
        rs2[i][0].x += e0; rs2[i][0].y += e1;
        rs2[i][1].x += e2; rs2[i][1].y += e3;
        cs2[j].x += e0 + e2; cs2[j].y += e1 + e3;
      }
    }
#pragma unroll
    for (int j = 0; j < 4; ++j) {
      float c = cs2[j].x + cs2[j].y;
      c += __shfl_xor(c, 16);
      c += __shfl_xor(c, 32);
      if (q == 0) atomicAdd(&colacc[t * 64 + j * 16 + l15], c);
    }
  }

  __syncthreads();
  // flush colsum partials (non-atomic: (stripe, split) slice is unique)
  for (int i = tid; i < 1024; i += 256)
    cpart[(size_t)stripe * 8192 + colbase + i] = colacc[i];

  // rowsum: reduce over the 16 lanes (cols) of each quad, flush once
#pragma unroll
  for (int i = 0; i < 4; ++i)
#pragma unroll
    for (int p = 0; p < 2; ++p)
      for (int s = 1; s < 16; s <<= 1) {
        rs2[i][p].x += __shfl_xor(rs2[i][p].x, s);
        rs2[i][p].y += __shfl_xor(rs2[i][p].y, s);
      }
  if (l15 == 0) {
#pragma unroll
    for (int i = 0; i < 4; ++i) {
      int rbase = (size_t)0 + stripe * 256 + wv * 64 + i * 16 + q * 4;
      rpart[(size_t)split * N_ROWS + rbase + 0] = rs2[i][0].x;
      rpart[(size_t)split * N_ROWS + rbase + 1] = rs2[i][0].y;
      rpart[(size_t)split * N_ROWS + rbase + 2] = rs2[i][1].x;
      rpart[(size_t)split * N_ROWS + rbase + 3] = rs2[i][1].y;
    }
  }
#undef STAGE
}

// ---------------------------------------------------------------------------
// fin1: blocks 0..63 rows (sum 8 partials, log, block-reduce);
//       blocks 64..95 cols (sum 64 partials, log, block-reduce) -> lpart[96]
// ---------------------------------------------------------------------------
__global__ void fin1(const float* __restrict__ rpart, const float* __restrict__ cpart,
                     double* __restrict__ lpart) {
  const int tid = threadIdx.x, b = blockIdx.x;
  double v;
  if (b < 64) {
    int row = b * 256 + tid;
    float s = 0.f;
#pragma unroll
    for (int p = 0; p < SPLITS; ++p) s += rpart[(size_t)p * N_ROWS + row];
    v = (double)logf(s);
  } else {
    int col = (b - 64) * 256 + tid;
    float s = 0.f;
#pragma unroll
    for (int p = 0; p < STRIPES; ++p) s += cpart[(size_t)p * M_COLS + col];
    v = (double)logf(s);
  }
  __shared__ double red[256];
  red[tid] = v;
  __syncthreads();
  for (int s = 128; s > 0; s >>= 1) {
    if (tid < s) red[tid] += red[tid + s];
    __syncthreads();
  }
  if (tid == 0) lpart[b] = red[0];
}

__global__ void fin2(const double* __restrict__ lpart,
                     const float* __restrict__ log_sigma, float* __restrict__ out) {
  const int tid = threadIdx.x;
  float lsv = log_sigma[0];
  float cst = 0.5f * 128.0f * (2.0f * lsv - 1.0f);
  if (tid == 0) {
    double s = 0.0;
    for (int i = 0; i < 64; ++i) s += lpart[i];
    out[0] = (float)(-(s / N_ROWS - (double)SHIFT)) + cst + logf((float)M_COLS);
  } else if (tid == 1) {
    double s = 0.0;
    for (int i = 64; i < 96; ++i) s += lpart[i];
    out[1] = (float)(-(s / M_COLS - (double)SHIFT)) + cst + logf((float)N_ROWS);
  }
}

extern "C" void kernel_launch(void* const* d_in, const int* in_sizes, int n_in,
                              void* d_out, int out_size, void* d_ws, size_t ws_size,
                              hipStream_t stream) {
  const float* z  = (const float*)d_in[0];
  const float* e  = (const float*)d_in[1];
  const float* ls = (const float*)d_in[2];
  float* out = (float*)d_out;
  char* ws = (char*)d_ws;
  u16*   zf    = (u16*)ws;                                  // 4 MB
  u16*   ef    = (u16*)(ws + (4u << 20));                   // 2 MB
  float* zsq   = (float*)(ws + (6u << 20));                 // 64 KB
  float* esq   = (float*)(ws + (6u << 20) + (64u << 10));   // 32 KB
  float* rpart = (float*)(ws + (6u << 20) + (96u << 10));   // 8*16384*4 = 512 KB
  float* cpart = (float*)(ws + (6u << 20) + (608u << 10));  // 64*8192*4 = 2 MB
  double* lpart = (double*)(ws + (6u << 20) + (608u << 10) + (2u << 20));  // 768 B

  prep<<<dim3(576), dim3(256), 0, stream>>>(z, e, zf, ef, zsq, esq);
  gemm_lse<<<dim3(STRIPES, SPLITS), dim3(256), 0, stream>>>(zf, ef, zsq, esq, ls, rpart, cpart);
  fin1<<<dim3(96), dim3(256), 0, stream>>>(rpart, cpart, lpart);
  fin2<<<dim3(1), dim3(64), 0, stream>>>(lpart, ls, out);
}